// Round 1
// baseline (8388.898 us; speedup 1.0000x reference)
//
#include <hip/hip_runtime.h>
#include <cstdint>
#include <cstddef>

#define BD 32
#define TD 4096
#define ID 256
#define OD 256

// f32 constants, computed in f64 and rounded (matches np.exp on f32 within <=1 ulp)
#define A_DEND 0.90483741803595957f   // exp(-1/10)
#define A_SYN  0.81873075307798182f   // exp(-1/5)
#define A_MEM  0.95122942450071402f   // exp(-1/20)
#define TWO_PI_F 6.28318530717958647692f
#define BASE_DTH 62.8318530717958647692f  // 2*pi*10
#define INV256 0.00390625f

// ---------------------------------------------------------------------------
// Phase A: soma[m][o] = x[m]·Ws[o];  u[m][o] = mean_n relu(x·Wb[n,o]) + mean_n relu(x·Wa[n,o])
// m = b*T + t (131072 rows). Tile: 64 m x 16 o per 256-thread block.
// x tile staged in LDS; weight rows streamed from global (L2-resident, 1.8 MB total).
// ---------------------------------------------------------------------------

#define DOT4(acc, xv, wv)               \
  acc = fmaf((xv).x, (wv).x, acc);      \
  acc = fmaf((xv).y, (wv).y, acc);      \
  acc = fmaf((xv).z, (wv).z, acc);      \
  acc = fmaf((xv).w, (wv).w, acc);

__global__ __launch_bounds__(256, 2)
void proj_kernel(const float* __restrict__ x,
                 const float* __restrict__ Ws,
                 const float* __restrict__ Wb,
                 const float* __restrict__ Wa,
                 float* __restrict__ soma_ws,
                 float* __restrict__ u_ws) {
  __shared__ float xl[64][260];  // +4 pad: breaks 4-way bank aliasing on b128 reads
  const int tid = threadIdx.x;
  const int o   = (blockIdx.x << 4) + (tid & 15);
  const int mq4 = (tid >> 4) << 2;      // this thread's first m-subrow (0,4,...,60)
  const int m0  = blockIdx.y << 6;

  // stage x tile 64x256 (coalesced float4)
  #pragma unroll
  for (int rep = 0; rep < 16; ++rep) {
    int lin = (rep << 8) + tid;        // 0..4095
    int r   = lin >> 6;
    int c4  = (lin & 63) << 2;
    float4 v = *(const float4*)(x + (size_t)(m0 + r) * ID + c4);
    *(float4*)(&xl[r][c4]) = v;
  }
  __syncthreads();

  const float* w0 = Ws + (size_t)o * ID;
  const float* w1 = Wb + (size_t)o * ID;
  const float* w2 = Wb + (size_t)(OD + o) * ID;
  const float* w3 = Wb + (size_t)(2 * OD + o) * ID;
  const float* w4 = Wb + (size_t)(3 * OD + o) * ID;
  const float* w5 = Wa + (size_t)o * ID;
  const float* w6 = Wa + (size_t)(OD + o) * ID;

  float acS[4], acB0[4], acB1[4], acB2[4], acB3[4], acA0[4], acA1[4];
  #pragma unroll
  for (int j = 0; j < 4; ++j) {
    acS[j] = 0.f; acB0[j] = 0.f; acB1[j] = 0.f; acB2[j] = 0.f; acB3[j] = 0.f;
    acA0[j] = 0.f; acA1[j] = 0.f;
  }

  for (int k = 0; k < ID; k += 4) {
    float4 xv0 = *(const float4*)(&xl[mq4 + 0][k]);
    float4 xv1 = *(const float4*)(&xl[mq4 + 1][k]);
    float4 xv2 = *(const float4*)(&xl[mq4 + 2][k]);
    float4 xv3 = *(const float4*)(&xl[mq4 + 3][k]);
    float4 vs  = *(const float4*)(w0 + k);
    float4 vb0 = *(const float4*)(w1 + k);
    float4 vb1 = *(const float4*)(w2 + k);
    float4 vb2 = *(const float4*)(w3 + k);
    float4 vb3 = *(const float4*)(w4 + k);
    float4 va0 = *(const float4*)(w5 + k);
    float4 va1 = *(const float4*)(w6 + k);
    DOT4(acS[0], xv0, vs)   DOT4(acS[1], xv1, vs)   DOT4(acS[2], xv2, vs)   DOT4(acS[3], xv3, vs)
    DOT4(acB0[0], xv0, vb0) DOT4(acB0[1], xv1, vb0) DOT4(acB0[2], xv2, vb0) DOT4(acB0[3], xv3, vb0)
    DOT4(acB1[0], xv0, vb1) DOT4(acB1[1], xv1, vb1) DOT4(acB1[2], xv2, vb1) DOT4(acB1[3], xv3, vb1)
    DOT4(acB2[0], xv0, vb2) DOT4(acB2[1], xv1, vb2) DOT4(acB2[2], xv2, vb2) DOT4(acB2[3], xv3, vb2)
    DOT4(acB3[0], xv0, vb3) DOT4(acB3[1], xv1, vb3) DOT4(acB3[2], xv2, vb3) DOT4(acB3[3], xv3, vb3)
    DOT4(acA0[0], xv0, va0) DOT4(acA0[1], xv1, va0) DOT4(acA0[2], xv2, va0) DOT4(acA0[3], xv3, va0)
    DOT4(acA1[0], xv0, va1) DOT4(acA1[1], xv1, va1) DOT4(acA1[2], xv2, va1) DOT4(acA1[3], xv3, va1)
  }

  const size_t mb = (size_t)(m0 + mq4) * OD + o;
  #pragma unroll
  for (int j = 0; j < 4; ++j) {
    float bm = ((fmaxf(acB0[j], 0.f) + fmaxf(acB1[j], 0.f)) +
                (fmaxf(acB2[j], 0.f) + fmaxf(acB3[j], 0.f))) * 0.25f;
    float am = (fmaxf(acA0[j], 0.f) + fmaxf(acA1[j], 0.f)) * 0.5f;
    soma_ws[mb + (size_t)j * OD] = acS[j];
    u_ws[mb + (size_t)j * OD]    = bm + am;
  }
}

// ---------------------------------------------------------------------------
// Phase B: sequential LIF + Kuramoto. 32 blocks x 1 wave; lane owns o=4l..4l+3.
// DPP wave64 sum for mean(cos th), mean(sin th) -- no LDS, no barriers.
// ---------------------------------------------------------------------------

#define DPP_ADD(v, ctrl, rm, bm, bc)                                          \
  v += __builtin_bit_cast(float, __builtin_amdgcn_update_dpp(                 \
           0, __builtin_bit_cast(int, v), ctrl, rm, bm, bc));

__device__ __forceinline__ float wave_sum64(float v) {
  DPP_ADD(v, 0x111, 0xf, 0xf, true)    // row_shr:1
  DPP_ADD(v, 0x112, 0xf, 0xf, true)    // row_shr:2
  DPP_ADD(v, 0x114, 0xf, 0xf, true)    // row_shr:4
  DPP_ADD(v, 0x118, 0xf, 0xf, true)    // row_shr:8
  DPP_ADD(v, 0x142, 0xa, 0xf, false)   // row_bcast:15 -> rows 1,3
  DPP_ADD(v, 0x143, 0xc, 0xf, false)   // row_bcast:31 -> rows 2,3
  return __builtin_bit_cast(float, __builtin_amdgcn_readlane(__builtin_bit_cast(int, v), 63));
}

__global__ __launch_bounds__(64, 1)
void dyn_kernel(const float* __restrict__ soma_ws,
                const float* __restrict__ u_ws,
                float* __restrict__ out) {
  // Match numpy's per-op rounding: no mul+add fusion except explicit fmaf.
  #pragma clang fp contract(off)
  const int b = blockIdx.x;
  const int l = threadIdx.x;

  const size_t base4 = ((size_t)b << 18) + l;        // float4 units: b*1048576/4 + lane
  const float4* S = (const float4*)soma_ws + base4;
  const float4* U = (const float4*)u_ws + base4;
  float4* Os = (float4*)out + base4;                 // spikes
  float4* Op = Os + ((size_t)1 << 23);               // phases   (+33554432 floats)
  float4* Om = Op + ((size_t)1 << 23);               // membrane

  float dend[4] = {0.f, 0.f, 0.f, 0.f};
  float syn[4]  = {0.f, 0.f, 0.f, 0.f};
  float mem[4]  = {0.f, 0.f, 0.f, 0.f};
  float th[4]   = {0.f, 0.f, 0.f, 0.f};

  const float bD = 1.0f - A_DEND;   // exact (Sterbenz)

  float4 ps[4], pu[4];
  #pragma unroll
  for (int i = 0; i < 4; ++i) { ps[i] = S[(size_t)i * 64]; pu[i] = U[(size_t)i * 64]; }

  for (int t4 = 0; t4 < TD / 4; ++t4) {
    float4 cs[4], cu[4];
    #pragma unroll
    for (int i = 0; i < 4; ++i) { cs[i] = ps[i]; cu[i] = pu[i]; }
    if (t4 < TD / 4 - 1) {   // prefetch next 4 steps (one chunk ahead hides HBM latency)
      #pragma unroll
      for (int i = 0; i < 4; ++i) {
        ps[i] = S[(size_t)(t4 * 4 + 4 + i) * 64];
        pu[i] = U[(size_t)(t4 * 4 + 4 + i) * 64];
      }
    }
    #pragma unroll
    for (int i = 0; i < 4; ++i) {
      const int t = (t4 << 2) + i;
      const float* sv = &cs[i].x;
      const float* uv = &cu[i].x;
      float spk[4], cc[4], ss[4];
      #pragma unroll
      for (int j = 0; j < 4; ++j) {
        // dend = aD*dend + (1-aD)*u   (separate roundings, like np)
        float t1 = A_DEND * dend[j];
        float t2 = bD * uv[j];
        dend[j] = t1 + t2;
        float drive = sv[j] + 0.5f * dend[j];   // 0.5* exact
        syn[j] = (A_SYN * syn[j]) + drive;
        mem[j] = (A_MEM * mem[j]) + syn[j];
        float v = mem[j] - 1.0f;
        // spike_fn forward: s_soft + (s_hard - s_soft), with its fp residual
        float sg = 1.0f / (1.0f + __expf(-4.0f * v));
        float hh = (v > 0.0f) ? 1.0f : 0.0f;
        float sp = sg + (hh - sg);
        mem[j] = mem[j] - sp;                   // reset by subtraction
        spk[j] = sp;
        cc[j] = __cosf(th[j]);
        ss[j] = __sinf(th[j]);
      }
      float csum = (cc[0] + cc[1]) + (cc[2] + cc[3]);
      float ssum = (ss[0] + ss[1]) + (ss[2] + ss[3]);
      float cS = wave_sum64(csum);
      float sS = wave_sum64(ssum);
      #pragma unroll
      for (int j = 0; j < 4; ++j) {
        // K*r*sin(psi - th) == s_mean*cos(th) - c_mean*sin(th)
        float coup = (sS * cc[j] - cS * ss[j]) * INV256;
        float dth = (BASE_DTH + coup) + spk[j];
        th[j] = th[j] + 0.001f * dth;
        th[j] = (th[j] >= TWO_PI_F) ? (th[j] - TWO_PI_F) : th[j];  // == np.mod (exact)
      }
      float4 so = {spk[0], spk[1], spk[2], spk[3]};
      float4 po = {th[0], th[1], th[2], th[3]};
      float4 mo = {mem[0], mem[1], mem[2], mem[3]};
      Os[(size_t)t * 64] = so;
      Op[(size_t)t * 64] = po;
      Om[(size_t)t * 64] = mo;
    }
  }
}

// ---------------------------------------------------------------------------

extern "C" void kernel_launch(void* const* d_in, const int* in_sizes, int n_in,
                              void* d_out, int out_size, void* d_ws, size_t ws_size,
                              hipStream_t stream) {
  const float* x  = (const float*)d_in[0];
  const float* Ws = (const float*)d_in[1];
  const float* Wb = (const float*)d_in[2];
  const float* Wa = (const float*)d_in[3];

  float* soma_ws = (float*)d_ws;
  float* u_ws    = soma_ws + (size_t)BD * TD * OD;   // +33554432 floats (268 MB total ws)
  float* out     = (float*)d_out;

  dim3 gA(OD / 16, (BD * TD) / 64, 1);   // (16, 2048)
  proj_kernel<<<gA, 256, 0, stream>>>(x, Ws, Wb, Wa, soma_ws, u_ws);
  dyn_kernel<<<BD, 64, 0, stream>>>(soma_ws, u_ws, out);
}